// Round 3
// baseline (427.415 us; speedup 1.0000x reference)
//
#include <hip/hip_runtime.h>
#include <hip/hip_bf16.h>

typedef __bf16 bf16_t;
typedef __bf16 bf16x8 __attribute__((ext_vector_type(8)));
typedef float f32x4 __attribute__((ext_vector_type(4)));

#define MFMA16(a, b, c) __builtin_amdgcn_mfma_f32_16x16x32_bf16((a), (b), (c), 0, 0, 0)

__device__ __forceinline__ void gload16(const bf16_t* g, bf16_t* l) {
  __builtin_amdgcn_global_load_lds((const __attribute__((address_space(1))) void*)g,
                                   (__attribute__((address_space(3))) void*)l,
                                   16, 0, 0);
}

__device__ __forceinline__ float fexp2(float x) {
  float r;
  asm("v_exp_f32 %0, %1" : "=v"(r) : "v"(x));
  return r;
}

// ---------------------------------------------------------------- prep ----
__global__ void __launch_bounds__(256)
prep_kernel(const float* __restrict__ x, const float* __restrict__ lA,
            const float* __restrict__ lB, const float* __restrict__ Wq,
            const float* __restrict__ Wp,
            bf16_t* __restrict__ xh, bf16_t* __restrict__ We,
            bf16_t* __restrict__ Wph) {
  const int bid = blockIdx.x, tid = threadIdx.x;
  if (bid < 4096) {
    const size_t i = ((size_t)bid * 256 + tid) * 8;
    const float4 f0 = ((const float4*)(x + i))[0];
    const float4 f1 = ((const float4*)(x + i))[1];
    alignas(16) bf16_t o[8] = {(bf16_t)f0.x, (bf16_t)f0.y, (bf16_t)f0.z, (bf16_t)f0.w,
                               (bf16_t)f1.x, (bf16_t)f1.y, (bf16_t)f1.z, (bf16_t)f1.w};
    *(uint4*)(xh + i) = *(const uint4*)o;
  } else if (bid < 7168) {
    const int g = (bid - 4096) * 256 + tid;
    const int e = g >> 8;
    const int d4 = (g & 255) * 4;
    float4 a = ((const float4*)(Wq + (size_t)e * 1024 + d4))[0];
#pragma unroll
    for (int r8 = 0; r8 < 8; ++r8) {
      const float sc = 0.125f * lB[e * 8 + r8];
      const float4 av = ((const float4*)(lA + r8 * 1024 + d4))[0];
      a.x += sc * av.x; a.y += sc * av.y; a.z += sc * av.z; a.w += sc * av.w;
    }
    alignas(8) bf16_t o[4] = {(bf16_t)a.x, (bf16_t)a.y, (bf16_t)a.z, (bf16_t)a.w};
    *(uint2*)(We + (size_t)e * 1024 + d4) = *(const uint2*)o;
  } else {
    const size_t i = ((size_t)(bid - 7168) * 256 + tid) * 8;
    const float4 f0 = ((const float4*)(Wp + i))[0];
    const float4 f1 = ((const float4*)(Wp + i))[1];
    alignas(16) bf16_t o[8] = {(bf16_t)f0.x, (bf16_t)f0.y, (bf16_t)f0.z, (bf16_t)f0.w,
                               (bf16_t)f1.x, (bf16_t)f1.y, (bf16_t)f1.z, (bf16_t)f1.w};
    *(uint4*)(Wph + i) = *(const uint4*)o;
  }
}

// ---------------------------------------------------------------- GEMM ----
// C[m][n] = sum_d A[m][d]*Bw[n][d]; 128x128 tile, 4 waves, dbuf LDS.
// EPI 0: +bias; Q rows pre-scaled by log2(e)/8; scatter Q/K/Vt (bf16)
// EPI 1: +bias, fp32 store
template <int EPI>
__global__ void __launch_bounds__(256)
gemm128(const bf16_t* __restrict__ A, const bf16_t* __restrict__ Bw,
        const float* __restrict__ bias, bf16_t* __restrict__ Qb,
        bf16_t* __restrict__ Kb, bf16_t* __restrict__ Vt,
        float* __restrict__ Obuf) {
  __shared__ bf16_t Asm[2][128 * 32];
  __shared__ bf16_t Bsm[2][128 * 32];
  const int tid = threadIdx.x;
  const int lane = tid & 63;
  const int wv = tid >> 6;
  const int wm = (wv >> 1) * 64;
  const int wn = (wv & 1) * 64;
  const int tm = blockIdx.x * 128;
  const int tn = blockIdx.y * 128;
  const int K = 1024;
  const int r = lane & 15, g = lane >> 4;

  const int srow = tid >> 2;
  const int scol = (tid & 3) * 8;
  const bf16_t* gA = A + (size_t)(tm + srow) * K + scol;
  const bf16_t* gB = Bw + (size_t)(tn + srow) * K + scol;

  f32x4 acc[4][4] = {};

  auto stage = [&](int kt, int buf) {
    const int k0 = kt * 32;
    bf16_t* la = &Asm[buf][wv * 512];
    bf16_t* lb = &Bsm[buf][wv * 512];
    gload16(gA + k0, la);
    gload16(gA + (size_t)64 * K + k0, la + 2048);
    gload16(gB + k0, lb);
    gload16(gB + (size_t)64 * K + k0, lb + 2048);
  };

  auto compute = [&](int buf) {
    bf16x8 af[4], bff[4];
#pragma unroll
    for (int mt = 0; mt < 4; ++mt)
      af[mt] = *(const bf16x8*)&Asm[buf][(wm + mt * 16 + r) * 32 + g * 8];
#pragma unroll
    for (int nt = 0; nt < 4; ++nt)
      bff[nt] = *(const bf16x8*)&Bsm[buf][(wn + nt * 16 + r) * 32 + g * 8];
#pragma unroll
    for (int mt = 0; mt < 4; ++mt)
#pragma unroll
      for (int nt = 0; nt < 4; ++nt)
        acc[mt][nt] = MFMA16(af[mt], bff[nt], acc[mt][nt]);
  };

  stage(0, 0);
  __syncthreads();
  int buf = 0;
  for (int kt = 0; kt < 31; ++kt) {
    stage(kt + 1, buf ^ 1);
    compute(buf);
    __syncthreads();
    buf ^= 1;
  }
  compute(buf);

  if (EPI == 0) {
    const int which = tn >> 10;
    const float qs = (which == 0) ? 0.18033688011f : 1.0f;  // log2(e)/8 folded into Q
#pragma unroll
    for (int nt = 0; nt < 4; ++nt) {
      const int e = tn + wn + nt * 16 + r;
      const float bv = bias[e];
      const int h = (e >> 6) & 15;
      const int hd = e & 63;
#pragma unroll
      for (int mt = 0; mt < 4; ++mt) {
        const int m0 = tm + wm + mt * 16 + g * 4;
        const int b = m0 >> 11;
        const int s0 = m0 & 2047;
        const size_t bh = (size_t)(b * 16 + h);
        if (which == 2) {
          alignas(8) bf16_t tmp[4];
#pragma unroll
          for (int j = 0; j < 4; ++j) tmp[j] = (bf16_t)(acc[mt][nt][j] + bv);
          *(uint2*)&Vt[(bh * 64 + hd) * 2048 + s0] = *(const uint2*)tmp;
        } else {
          bf16_t* dst = (which == 0) ? Qb : Kb;
#pragma unroll
          for (int j = 0; j < 4; ++j)
            dst[(bh * 2048 + s0 + j) * 64 + hd] = (bf16_t)((acc[mt][nt][j] + bv) * qs);
        }
      }
    }
  } else {
#pragma unroll
    for (int nt = 0; nt < 4; ++nt) {
      const int e = tn + wn + nt * 16 + r;
      const float bv = bias[e];
#pragma unroll
      for (int mt = 0; mt < 4; ++mt) {
#pragma unroll
        for (int j = 0; j < 4; ++j) {
          const int m = tm + wm + mt * 16 + g * 4 + j;
          Obuf[(size_t)m * 1024 + e] = acc[mt][nt][j] + bv;
        }
      }
    }
  }
}

// ----------------------------------------------------------- attention ----
// grid (64 bh, 16 qtiles), 4 independent waves x 32 q-rows. No K/V staging
// (L2-resident: 512KB/bh, all 16 q-tiles of a bh on one XCD). Swapped QK^T
// (mfma(K,Q)) makes each lane hold 4 consecutive k for one q: P stores are
// packed ds_write_b64, PV A-frags are ds_read_b128. Unnormalized softmax
// (Q pre-scaled by log2(e)/8 -> raw v_exp_f32); row-sum reduced at end.
__global__ void __launch_bounds__(256, 4)
attn_kernel(const bf16_t* __restrict__ Qb, const bf16_t* __restrict__ Kb,
            const bf16_t* __restrict__ Vt, bf16_t* __restrict__ AO) {
  __shared__ bf16_t Ps[4][32 * 72];  // stride 72: q,q+16 alias only (2-way, free)

  const int tid = threadIdx.x, lane = tid & 63, wv = tid >> 6;
  const int bh = blockIdx.x;
  const int qt = blockIdx.y;
  const int r = lane & 15, g = lane >> 4;

  const size_t qrow0 = (size_t)bh * 2048 + qt * 128 + wv * 32;
  bf16x8 qf[2][2];
#pragma unroll
  for (int mt2 = 0; mt2 < 2; ++mt2)
#pragma unroll
    for (int kc = 0; kc < 2; ++kc)
      qf[mt2][kc] = *(const bf16x8*)&Qb[(qrow0 + mt2 * 16 + r) * 64 + kc * 32 + g * 8];

  const bf16_t* gK = Kb + (size_t)bh * 2048 * 64;
  const bf16_t* gV = Vt + (size_t)bh * 64 * 2048;
  bf16_t* myP = &Ps[wv][0];

  f32x4 oacc[2][4] = {};
  float lsum[2] = {0.f, 0.f};

  for (int t = 0; t < 32; ++t) {
    const int k0 = t * 64;
    // ---- S^T = K Q^T : lane holds S[q=mt2*16+r][k=ntk*16+g*4+j]
    f32x4 sacc[2][4] = {};
#pragma unroll
    for (int kc = 0; kc < 2; ++kc) {
      bf16x8 kf[4];
#pragma unroll
      for (int ntk = 0; ntk < 4; ++ntk)
        kf[ntk] = *(const bf16x8*)&gK[(size_t)(k0 + ntk * 16 + r) * 64 + kc * 32 + g * 8];
      __builtin_amdgcn_s_setprio(1);
#pragma unroll
      for (int ntk = 0; ntk < 4; ++ntk)
#pragma unroll
        for (int mt2 = 0; mt2 < 2; ++mt2)
          sacc[mt2][ntk] = MFMA16(kf[ntk], qf[mt2][kc], sacc[mt2][ntk]);
      __builtin_amdgcn_s_setprio(0);
    }
    // ---- P = exp(S'), packed b64 stores, lane-local partial row-sums
#pragma unroll
    for (int mt2 = 0; mt2 < 2; ++mt2)
#pragma unroll
      for (int ntk = 0; ntk < 4; ++ntk) {
        const f32x4 s4 = sacc[mt2][ntk];
        const float p0 = fexp2(s4[0]), p1 = fexp2(s4[1]);
        const float p2 = fexp2(s4[2]), p3 = fexp2(s4[3]);
        lsum[mt2] += (p0 + p1) + (p2 + p3);
        alignas(8) bf16_t pb[4] = {(bf16_t)p0, (bf16_t)p1, (bf16_t)p2, (bf16_t)p3};
        *(uint2*)&myP[(mt2 * 16 + r) * 72 + ntk * 16 + g * 4] = *(const uint2*)pb;
      }
    // ---- O += P V
#pragma unroll
    for (int kc = 0; kc < 2; ++kc) {
      bf16x8 vf[4], pf[2];
#pragma unroll
      for (int nth = 0; nth < 4; ++nth)
        vf[nth] = *(const bf16x8*)&gV[(size_t)(nth * 16 + r) * 2048 + k0 + kc * 32 + g * 8];
#pragma unroll
      for (int mt2 = 0; mt2 < 2; ++mt2)
        pf[mt2] = *(const bf16x8*)&myP[(mt2 * 16 + r) * 72 + kc * 32 + g * 8];
      __builtin_amdgcn_s_setprio(1);
#pragma unroll
      for (int nth = 0; nth < 4; ++nth)
#pragma unroll
        for (int mt2 = 0; mt2 < 2; ++mt2)
          oacc[mt2][nth] = MFMA16(pf[mt2], vf[nth], oacc[mt2][nth]);
      __builtin_amdgcn_s_setprio(0);
    }
  }

  // full row-sums: combine the 4 g-groups (lanes r, r+16, r+32, r+48)
#pragma unroll
  for (int mt2 = 0; mt2 < 2; ++mt2) {
    lsum[mt2] += __shfl_xor(lsum[mt2], 16, 64);
    lsum[mt2] += __shfl_xor(lsum[mt2], 32, 64);
  }

  const int b = bh >> 4, h = bh & 15;
#pragma unroll
  for (int mt2 = 0; mt2 < 2; ++mt2)
#pragma unroll
    for (int j = 0; j < 4; ++j) {
      // sum for q=mt2*16+g*4+j lives at lane (g*4+j) (any g-group)
      const float sum = __shfl(lsum[mt2], g * 4 + j, 64);
      const float inv = __builtin_amdgcn_rcpf(sum);
      const int s = qt * 128 + wv * 32 + mt2 * 16 + g * 4 + j;
#pragma unroll
      for (int nth = 0; nth < 4; ++nth) {
        const int col = h * 64 + nth * 16 + r;
        AO[((size_t)(b * 2048 + s)) * 1024 + col] = (bf16_t)(oacc[mt2][nth][j] * inv);
      }
    }
}

// -------------------------------------------------------------- launch ----
extern "C" void kernel_launch(void* const* d_in, const int* in_sizes, int n_in,
                              void* d_out, int out_size, void* d_ws, size_t ws_size,
                              hipStream_t stream) {
  const float* x = (const float*)d_in[0];
  const float* lA = (const float*)d_in[1];
  const float* lB = (const float*)d_in[2];
  const float* Wq = (const float*)d_in[3];
  const float* bq = (const float*)d_in[4];
  const float* Wp = (const float*)d_in[5];
  const float* bp = (const float*)d_in[6];

  char* ws = (char*)d_ws;
  bf16_t* xh  = (bf16_t*)(ws);                      // 16 MiB
  bf16_t* We  = (bf16_t*)(ws + 16777216);           // 6 MiB
  bf16_t* Wph = (bf16_t*)(ws + 23068672);           // 2 MiB
  bf16_t* Qb  = (bf16_t*)(ws + 25165824);           // 16 MiB [b,h,s,hd] (pre-scaled)
  bf16_t* Kb  = (bf16_t*)(ws + 41943040);           // 16 MiB [b,h,s,hd]
  bf16_t* Vt  = (bf16_t*)(ws + 58720256);           // 16 MiB [b,h,hd,s]
  bf16_t* AO  = (bf16_t*)(ws + 75497472);           // 16 MiB [tok,1024]

  prep_kernel<<<7680, 256, 0, stream>>>(x, lA, lB, Wq, Wp, xh, We, Wph);
  gemm128<0><<<dim3(64, 24), 256, 0, stream>>>(xh, We, bq, Qb, Kb, Vt, nullptr);
  attn_kernel<<<dim3(64, 16), 256, 0, stream>>>(Qb, Kb, Vt, AO);
  gemm128<1><<<dim3(64, 8), 256, 0, stream>>>(AO, Wph, bp, nullptr, nullptr, nullptr,
                                              (float*)d_out);
}

// Round 4
// 292.056 us; speedup vs baseline: 1.4635x; 1.4635x over previous
//
#include <hip/hip_runtime.h>
#include <hip/hip_bf16.h>

typedef __bf16 bf16_t;
typedef __bf16 bf16x8 __attribute__((ext_vector_type(8)));
typedef float f32x4 __attribute__((ext_vector_type(4)));

#define MFMA16(a, b, c) __builtin_amdgcn_mfma_f32_16x16x32_bf16((a), (b), (c), 0, 0, 0)

__device__ __forceinline__ void gload16(const bf16_t* g, bf16_t* l) {
  __builtin_amdgcn_global_load_lds((const __attribute__((address_space(1))) void*)g,
                                   (__attribute__((address_space(3))) void*)l,
                                   16, 0, 0);
}

__device__ __forceinline__ float fexp2(float x) {
  float r;
  asm("v_exp_f32 %0, %1" : "=v"(r) : "v"(x));
  return r;
}

// ---------------------------------------------------------------- prep ----
__global__ void __launch_bounds__(256)
prep_kernel(const float* __restrict__ x, const float* __restrict__ lA,
            const float* __restrict__ lB, const float* __restrict__ Wq,
            const float* __restrict__ Wp,
            bf16_t* __restrict__ xh, bf16_t* __restrict__ We,
            bf16_t* __restrict__ Wph) {
  const int bid = blockIdx.x, tid = threadIdx.x;
  if (bid < 4096) {
    const size_t i = ((size_t)bid * 256 + tid) * 8;
    const float4 f0 = ((const float4*)(x + i))[0];
    const float4 f1 = ((const float4*)(x + i))[1];
    alignas(16) bf16_t o[8] = {(bf16_t)f0.x, (bf16_t)f0.y, (bf16_t)f0.z, (bf16_t)f0.w,
                               (bf16_t)f1.x, (bf16_t)f1.y, (bf16_t)f1.z, (bf16_t)f1.w};
    *(uint4*)(xh + i) = *(const uint4*)o;
  } else if (bid < 7168) {
    const int g = (bid - 4096) * 256 + tid;
    const int e = g >> 8;
    const int d4 = (g & 255) * 4;
    float4 a = ((const float4*)(Wq + (size_t)e * 1024 + d4))[0];
#pragma unroll
    for (int r8 = 0; r8 < 8; ++r8) {
      const float sc = 0.125f * lB[e * 8 + r8];
      const float4 av = ((const float4*)(lA + r8 * 1024 + d4))[0];
      a.x += sc * av.x; a.y += sc * av.y; a.z += sc * av.z; a.w += sc * av.w;
    }
    alignas(8) bf16_t o[4] = {(bf16_t)a.x, (bf16_t)a.y, (bf16_t)a.z, (bf16_t)a.w};
    *(uint2*)(We + (size_t)e * 1024 + d4) = *(const uint2*)o;
  } else {
    const size_t i = ((size_t)(bid - 7168) * 256 + tid) * 8;
    const float4 f0 = ((const float4*)(Wp + i))[0];
    const float4 f1 = ((const float4*)(Wp + i))[1];
    alignas(16) bf16_t o[8] = {(bf16_t)f0.x, (bf16_t)f0.y, (bf16_t)f0.z, (bf16_t)f0.w,
                               (bf16_t)f1.x, (bf16_t)f1.y, (bf16_t)f1.z, (bf16_t)f1.w};
    *(uint4*)(Wph + i) = *(const uint4*)o;
  }
}

// ---------------------------------------------------------------- GEMM ----
template <int EPI>
__global__ void __launch_bounds__(256)
gemm128(const bf16_t* __restrict__ A, const bf16_t* __restrict__ Bw,
        const float* __restrict__ bias, bf16_t* __restrict__ Qb,
        bf16_t* __restrict__ Kb, bf16_t* __restrict__ Vt,
        float* __restrict__ Obuf) {
  __shared__ bf16_t Asm[2][128 * 32];
  __shared__ bf16_t Bsm[2][128 * 32];
  const int tid = threadIdx.x;
  const int lane = tid & 63;
  const int wv = tid >> 6;
  const int wm = (wv >> 1) * 64;
  const int wn = (wv & 1) * 64;
  const int tm = blockIdx.x * 128;
  const int tn = blockIdx.y * 128;
  const int K = 1024;
  const int r = lane & 15, g = lane >> 4;

  const int srow = tid >> 2;
  const int scol = (tid & 3) * 8;
  const bf16_t* gA = A + (size_t)(tm + srow) * K + scol;
  const bf16_t* gB = Bw + (size_t)(tn + srow) * K + scol;

  f32x4 acc[4][4] = {};

  auto stage = [&](int kt, int buf) {
    const int k0 = kt * 32;
    bf16_t* la = &Asm[buf][wv * 512];
    bf16_t* lb = &Bsm[buf][wv * 512];
    gload16(gA + k0, la);
    gload16(gA + (size_t)64 * K + k0, la + 2048);
    gload16(gB + k0, lb);
    gload16(gB + (size_t)64 * K + k0, lb + 2048);
  };

  auto compute = [&](int buf) {
    bf16x8 af[4], bff[4];
#pragma unroll
    for (int mt = 0; mt < 4; ++mt)
      af[mt] = *(const bf16x8*)&Asm[buf][(wm + mt * 16 + r) * 32 + g * 8];
#pragma unroll
    for (int nt = 0; nt < 4; ++nt)
      bff[nt] = *(const bf16x8*)&Bsm[buf][(wn + nt * 16 + r) * 32 + g * 8];
#pragma unroll
    for (int mt = 0; mt < 4; ++mt)
#pragma unroll
      for (int nt = 0; nt < 4; ++nt)
        acc[mt][nt] = MFMA16(af[mt], bff[nt], acc[mt][nt]);
  };

  stage(0, 0);
  __syncthreads();
  int buf = 0;
  for (int kt = 0; kt < 31; ++kt) {
    stage(kt + 1, buf ^ 1);
    compute(buf);
    __syncthreads();
    buf ^= 1;
  }
  compute(buf);

  if (EPI == 0) {
    const int which = tn >> 10;
    const float qs = (which == 0) ? 0.18033688011f : 1.0f;  // log2(e)/8 folded into Q
#pragma unroll
    for (int nt = 0; nt < 4; ++nt) {
      const int e = tn + wn + nt * 16 + r;
      const float bv = bias[e];
      const int h = (e >> 6) & 15;
      const int hd = e & 63;
#pragma unroll
      for (int mt = 0; mt < 4; ++mt) {
        const int m0 = tm + wm + mt * 16 + g * 4;
        const int b = m0 >> 11;
        const int s0 = m0 & 2047;
        const size_t bh = (size_t)(b * 16 + h);
        if (which == 2) {
          alignas(8) bf16_t tmp[4];
#pragma unroll
          for (int j = 0; j < 4; ++j) tmp[j] = (bf16_t)(acc[mt][nt][j] + bv);
          *(uint2*)&Vt[(bh * 64 + hd) * 2048 + s0] = *(const uint2*)tmp;
        } else {
          bf16_t* dst = (which == 0) ? Qb : Kb;
#pragma unroll
          for (int j = 0; j < 4; ++j)
            dst[(bh * 2048 + s0 + j) * 64 + hd] = (bf16_t)((acc[mt][nt][j] + bv) * qs);
        }
      }
    }
  } else {
#pragma unroll
    for (int nt = 0; nt < 4; ++nt) {
      const int e = tn + wn + nt * 16 + r;
      const float bv = bias[e];
#pragma unroll
      for (int mt = 0; mt < 4; ++mt) {
#pragma unroll
        for (int j = 0; j < 4; ++j) {
          const int m = tm + wm + mt * 16 + g * 4 + j;
          Obuf[(size_t)m * 1024 + e] = acc[mt][nt][j] + bv;
        }
      }
    }
  }
}

// ----------------------------------------------------------- attention ----
// R0 structure (dbuf gload_lds K/V staging — keeps L2 latency off the
// critical path) + R1 P-path (swapped QK^T -> packed b64 P stores, raw
// v_exp_f32 on pre-scaled Q, 2-reg lsum). Ps uses an XOR swizzle
// (group ^= q&7) that is analytically min-cycle for both the b64 write
// (4 dw/bank) and b128 read (8 dw/bank) patterns.
__global__ void __launch_bounds__(256, 3)
attn_kernel(const bf16_t* __restrict__ Qb, const bf16_t* __restrict__ Kb,
            const bf16_t* __restrict__ Vt, bf16_t* __restrict__ AO) {
  __shared__ bf16_t Ks[2][64 * 64];
  __shared__ bf16_t Vs[2][64 * 64];
  __shared__ bf16_t Ps[4][32 * 64];

  const int tid = threadIdx.x, lane = tid & 63, wv = tid >> 6;
  const int bh = blockIdx.x;
  const int qt = blockIdx.y;
  const int r = lane & 15, g = lane >> 4;

  const size_t qrow0 = (size_t)bh * 2048 + qt * 128 + wv * 32;
  bf16x8 qf[2][2];
#pragma unroll
  for (int mt2 = 0; mt2 < 2; ++mt2)
#pragma unroll
    for (int kc = 0; kc < 2; ++kc)
      qf[mt2][kc] = *(const bf16x8*)&Qb[(qrow0 + mt2 * 16 + r) * 64 + kc * 32 + g * 8];

  // K/V staging: XOR source pre-swizzle, linear LDS dest (rule 21)
  const int krow = tid >> 3;                       // 0..31
  const int kcg = ((tid & 7) ^ (krow & 7)) * 8;    // swizzled source column
  const bf16_t* gK = Kb + (size_t)bh * 2048 * 64;
  const bf16_t* gV = Vt + (size_t)bh * 64 * 2048;
  bf16_t* myP = &Ps[wv][0];

  auto stageKV = [&](int t, int buf) {
    const int kv0 = t * 64;
    gload16(gK + (size_t)(kv0 + krow) * 64 + kcg, &Ks[buf][wv * 512]);
    gload16(gK + (size_t)(kv0 + 32 + krow) * 64 + kcg, &Ks[buf][2048 + wv * 512]);
    gload16(gV + (size_t)krow * 2048 + kv0 + kcg, &Vs[buf][wv * 512]);
    gload16(gV + (size_t)(32 + krow) * 2048 + kv0 + kcg, &Vs[buf][2048 + wv * 512]);
  };

  f32x4 oacc[2][4] = {};
  float lsum[2] = {0.f, 0.f};

  stageKV(0, 0);
  __syncthreads();
  int buf = 0;
  for (int t = 0; t < 32; ++t) {
    if (t < 31) stageKV(t + 1, buf ^ 1);
    // ---- S^T = K Q^T : lane holds S[q=mt2*16+r][k=ntk*16+g*4+j]
    f32x4 sacc[2][4] = {};
#pragma unroll
    for (int kc = 0; kc < 2; ++kc) {
      bf16x8 kf[4];
#pragma unroll
      for (int ntk = 0; ntk < 4; ++ntk) {
        const int row = ntk * 16 + r;
        const int cg = (kc * 4 + g) ^ (row & 7);
        kf[ntk] = *(const bf16x8*)&Ks[buf][row * 64 + cg * 8];
      }
      __builtin_amdgcn_s_setprio(1);
#pragma unroll
      for (int ntk = 0; ntk < 4; ++ntk)
#pragma unroll
        for (int mt2 = 0; mt2 < 2; ++mt2)
          sacc[mt2][ntk] = MFMA16(kf[ntk], qf[mt2][kc], sacc[mt2][ntk]);
      __builtin_amdgcn_s_setprio(0);
    }
    // ---- P = exp(S'), packed b64 stores into XOR-swizzled Ps
#pragma unroll
    for (int mt2 = 0; mt2 < 2; ++mt2)
#pragma unroll
      for (int ntk = 0; ntk < 4; ++ntk) {
        const f32x4 s4 = sacc[mt2][ntk];
        const float p0 = fexp2(s4[0]), p1 = fexp2(s4[1]);
        const float p2 = fexp2(s4[2]), p3 = fexp2(s4[3]);
        lsum[mt2] += (p0 + p1) + (p2 + p3);
        alignas(8) bf16_t pb[4] = {(bf16_t)p0, (bf16_t)p1, (bf16_t)p2, (bf16_t)p3};
        const int q = mt2 * 16 + r;
        const int gw = (2 * ntk + (g >> 1)) ^ (r & 7);
        *(uint2*)&myP[q * 64 + gw * 8 + (g & 1) * 4] = *(const uint2*)pb;
      }
    // ---- O += P V
#pragma unroll
    for (int kc = 0; kc < 2; ++kc) {
      bf16x8 vf[4], pf[2];
#pragma unroll
      for (int nth = 0; nth < 4; ++nth) {
        const int hrow = nth * 16 + r;
        const int cg = (kc * 4 + g) ^ (hrow & 7);
        vf[nth] = *(const bf16x8*)&Vs[buf][hrow * 64 + cg * 8];
      }
#pragma unroll
      for (int mt2 = 0; mt2 < 2; ++mt2) {
        const int q = mt2 * 16 + r;
        const int gr = (kc * 4 + g) ^ (r & 7);
        pf[mt2] = *(const bf16x8*)&myP[q * 64 + gr * 8];
      }
      __builtin_amdgcn_s_setprio(1);
#pragma unroll
      for (int nth = 0; nth < 4; ++nth)
#pragma unroll
        for (int mt2 = 0; mt2 < 2; ++mt2)
          oacc[mt2][nth] = MFMA16(pf[mt2], vf[nth], oacc[mt2][nth]);
      __builtin_amdgcn_s_setprio(0);
    }
    __syncthreads();
    buf ^= 1;
  }

  // full row-sums: combine the 4 g-groups (lanes r, r+16, r+32, r+48)
#pragma unroll
  for (int mt2 = 0; mt2 < 2; ++mt2) {
    lsum[mt2] += __shfl_xor(lsum[mt2], 16, 64);
    lsum[mt2] += __shfl_xor(lsum[mt2], 32, 64);
  }

  const int b = bh >> 4, h = bh & 15;
#pragma unroll
  for (int mt2 = 0; mt2 < 2; ++mt2)
#pragma unroll
    for (int j = 0; j < 4; ++j) {
      const float sum = __shfl(lsum[mt2], g * 4 + j, 64);
      const float inv = __builtin_amdgcn_rcpf(sum);
      const int s = qt * 128 + wv * 32 + mt2 * 16 + g * 4 + j;
#pragma unroll
      for (int nth = 0; nth < 4; ++nth) {
        const int col = h * 64 + nth * 16 + r;
        AO[((size_t)(b * 2048 + s)) * 1024 + col] = (bf16_t)(oacc[mt2][nth][j] * inv);
      }
    }
}

// -------------------------------------------------------------- launch ----
extern "C" void kernel_launch(void* const* d_in, const int* in_sizes, int n_in,
                              void* d_out, int out_size, void* d_ws, size_t ws_size,
                              hipStream_t stream) {
  const float* x = (const float*)d_in[0];
  const float* lA = (const float*)d_in[1];
  const float* lB = (const float*)d_in[2];
  const float* Wq = (const float*)d_in[3];
  const float* bq = (const float*)d_in[4];
  const float* Wp = (const float*)d_in[5];
  const float* bp = (const float*)d_in[6];

  char* ws = (char*)d_ws;
  bf16_t* xh  = (bf16_t*)(ws);                      // 16 MiB
  bf16_t* We  = (bf16_t*)(ws + 16777216);           // 6 MiB
  bf16_t* Wph = (bf16_t*)(ws + 23068672);           // 2 MiB
  bf16_t* Qb  = (bf16_t*)(ws + 25165824);           // 16 MiB [b,h,s,hd] (pre-scaled)
  bf16_t* Kb  = (bf16_t*)(ws + 41943040);           // 16 MiB [b,h,s,hd]
  bf16_t* Vt  = (bf16_t*)(ws + 58720256);           // 16 MiB [b,h,hd,s]
  bf16_t* AO  = (bf16_t*)(ws + 75497472);           // 16 MiB [tok,1024]

  prep_kernel<<<7680, 256, 0, stream>>>(x, lA, lB, Wq, Wp, xh, We, Wph);
  gemm128<0><<<dim3(64, 24), 256, 0, stream>>>(xh, We, bq, Qb, Kb, Vt, nullptr);
  attn_kernel<<<dim3(64, 16), 256, 0, stream>>>(Qb, Kb, Vt, AO);
  gemm128<1><<<dim3(64, 8), 256, 0, stream>>>(AO, Wph, bp, nullptr, nullptr, nullptr,
                                              (float*)d_out);
}

// Round 6
// 287.566 us; speedup vs baseline: 1.4863x; 1.0156x over previous
//
#include <hip/hip_runtime.h>
#include <hip/hip_bf16.h>

typedef __bf16 bf16_t;
typedef __bf16 bf16x8 __attribute__((ext_vector_type(8)));
typedef float f32x4 __attribute__((ext_vector_type(4)));

#define MFMA16(a, b, c) __builtin_amdgcn_mfma_f32_16x16x32_bf16((a), (b), (c), 0, 0, 0)

__device__ __forceinline__ void gload16(const bf16_t* g, bf16_t* l) {
  __builtin_amdgcn_global_load_lds((const __attribute__((address_space(1))) void*)g,
                                   (__attribute__((address_space(3))) void*)l,
                                   16, 0, 0);
}

__device__ __forceinline__ float fexp2(float x) {
  float r;
  asm("v_exp_f32 %0, %1" : "=v"(r) : "v"(x));
  return r;
}

// ---------------------------------------------------------------- prep ----
__global__ void __launch_bounds__(256)
prep_kernel(const float* __restrict__ x, const float* __restrict__ lA,
            const float* __restrict__ lB, const float* __restrict__ Wq,
            const float* __restrict__ Wp,
            bf16_t* __restrict__ xh, bf16_t* __restrict__ We,
            bf16_t* __restrict__ Wph) {
  const int bid = blockIdx.x, tid = threadIdx.x;
  if (bid < 4096) {
    const size_t i = ((size_t)bid * 256 + tid) * 8;
    const float4 f0 = ((const float4*)(x + i))[0];
    const float4 f1 = ((const float4*)(x + i))[1];
    alignas(16) bf16_t o[8] = {(bf16_t)f0.x, (bf16_t)f0.y, (bf16_t)f0.z, (bf16_t)f0.w,
                               (bf16_t)f1.x, (bf16_t)f1.y, (bf16_t)f1.z, (bf16_t)f1.w};
    *(uint4*)(xh + i) = *(const uint4*)o;
  } else if (bid < 7168) {
    const int g = (bid - 4096) * 256 + tid;
    const int e = g >> 8;
    const int d4 = (g & 255) * 4;
    float4 a = ((const float4*)(Wq + (size_t)e * 1024 + d4))[0];
#pragma unroll
    for (int r8 = 0; r8 < 8; ++r8) {
      const float sc = 0.125f * lB[e * 8 + r8];
      const float4 av = ((const float4*)(lA + r8 * 1024 + d4))[0];
      a.x += sc * av.x; a.y += sc * av.y; a.z += sc * av.z; a.w += sc * av.w;
    }
    alignas(8) bf16_t o[4] = {(bf16_t)a.x, (bf16_t)a.y, (bf16_t)a.z, (bf16_t)a.w};
    *(uint2*)(We + (size_t)e * 1024 + d4) = *(const uint2*)o;
  } else {
    const size_t i = ((size_t)(bid - 7168) * 256 + tid) * 8;
    const float4 f0 = ((const float4*)(Wp + i))[0];
    const float4 f1 = ((const float4*)(Wp + i))[1];
    alignas(16) bf16_t o[8] = {(bf16_t)f0.x, (bf16_t)f0.y, (bf16_t)f0.z, (bf16_t)f0.w,
                               (bf16_t)f1.x, (bf16_t)f1.y, (bf16_t)f1.z, (bf16_t)f1.w};
    *(uint4*)(Wph + i) = *(const uint4*)o;
  }
}

// ---------------------------------------------------------------- GEMM ----
template <int EPI>
__global__ void __launch_bounds__(256)
gemm128(const bf16_t* __restrict__ A, const bf16_t* __restrict__ Bw,
        const float* __restrict__ bias, bf16_t* __restrict__ Qb,
        bf16_t* __restrict__ Kb, bf16_t* __restrict__ Vt,
        float* __restrict__ Obuf) {
  __shared__ bf16_t Asm[2][128 * 32];
  __shared__ bf16_t Bsm[2][128 * 32];
  const int tid = threadIdx.x;
  const int lane = tid & 63;
  const int wv = tid >> 6;
  const int wm = (wv >> 1) * 64;
  const int wn = (wv & 1) * 64;
  const int tm = blockIdx.x * 128;
  const int tn = blockIdx.y * 128;
  const int K = 1024;
  const int r = lane & 15, g = lane >> 4;

  const int srow = tid >> 2;
  const int scol = (tid & 3) * 8;
  const bf16_t* gA = A + (size_t)(tm + srow) * K + scol;
  const bf16_t* gB = Bw + (size_t)(tn + srow) * K + scol;

  f32x4 acc[4][4] = {};

  auto stage = [&](int kt, int buf) {
    const int k0 = kt * 32;
    bf16_t* la = &Asm[buf][wv * 512];
    bf16_t* lb = &Bsm[buf][wv * 512];
    gload16(gA + k0, la);
    gload16(gA + (size_t)64 * K + k0, la + 2048);
    gload16(gB + k0, lb);
    gload16(gB + (size_t)64 * K + k0, lb + 2048);
  };

  auto compute = [&](int buf) {
    bf16x8 af[4], bff[4];
#pragma unroll
    for (int mt = 0; mt < 4; ++mt)
      af[mt] = *(const bf16x8*)&Asm[buf][(wm + mt * 16 + r) * 32 + g * 8];
#pragma unroll
    for (int nt = 0; nt < 4; ++nt)
      bff[nt] = *(const bf16x8*)&Bsm[buf][(wn + nt * 16 + r) * 32 + g * 8];
#pragma unroll
    for (int mt = 0; mt < 4; ++mt)
#pragma unroll
      for (int nt = 0; nt < 4; ++nt)
        acc[mt][nt] = MFMA16(af[mt], bff[nt], acc[mt][nt]);
  };

  stage(0, 0);
  __syncthreads();
  int buf = 0;
  for (int kt = 0; kt < 31; ++kt) {
    stage(kt + 1, buf ^ 1);
    compute(buf);
    __syncthreads();
    buf ^= 1;
  }
  compute(buf);

  if (EPI == 0) {
    const int which = tn >> 10;
    const float qs = (which == 0) ? 0.18033688011f : 1.0f;  // log2(e)/8 folded into Q
#pragma unroll
    for (int nt = 0; nt < 4; ++nt) {
      const int e = tn + wn + nt * 16 + r;
      const float bv = bias[e];
      const int h = (e >> 6) & 15;
      const int hd = e & 63;
#pragma unroll
      for (int mt = 0; mt < 4; ++mt) {
        const int m0 = tm + wm + mt * 16 + g * 4;
        const int b = m0 >> 11;
        const int s0 = m0 & 2047;
        const size_t bh = (size_t)(b * 16 + h);
        if (which == 2) {
          alignas(8) bf16_t tmp[4];
#pragma unroll
          for (int j = 0; j < 4; ++j) tmp[j] = (bf16_t)(acc[mt][nt][j] + bv);
          *(uint2*)&Vt[(bh * 64 + hd) * 2048 + s0] = *(const uint2*)tmp;
        } else {
          bf16_t* dst = (which == 0) ? Qb : Kb;
#pragma unroll
          for (int j = 0; j < 4; ++j)
            dst[(bh * 2048 + s0 + j) * 64 + hd] = (bf16_t)((acc[mt][nt][j] + bv) * qs);
        }
      }
    }
  } else {
#pragma unroll
    for (int nt = 0; nt < 4; ++nt) {
      const int e = tn + wn + nt * 16 + r;
      const float bv = bias[e];
#pragma unroll
      for (int mt = 0; mt < 4; ++mt) {
#pragma unroll
        for (int j = 0; j < 4; ++j) {
          const int m = tm + wm + mt * 16 + g * 4 + j;
          Obuf[(size_t)m * 1024 + e] = acc[mt][nt][j] + bv;
        }
      }
    }
  }
}

// ----------------------------------------------------------- attention ----
// R4-verified structure: dbuf gload_lds K/V staging + swapped 16x16 QK^T
// (packed b64 P stores, raw v_exp_f32 on pre-scaled Q, 2-reg lsum), XOR-
// swizzled Ps. Only change vs R4: V-fragment reads hoisted ahead of the
// exp/pack section so they overlap the P write->read lgkm chain.
__global__ void __launch_bounds__(256, 3)
attn_kernel(const bf16_t* __restrict__ Qb, const bf16_t* __restrict__ Kb,
            const bf16_t* __restrict__ Vt, bf16_t* __restrict__ AO) {
  __shared__ bf16_t Ks[2][64 * 64];
  __shared__ bf16_t Vs[2][64 * 64];
  __shared__ bf16_t Ps[4][32 * 64];

  const int tid = threadIdx.x, lane = tid & 63, wv = tid >> 6;
  const int bh = blockIdx.x;
  const int qt = blockIdx.y;
  const int r = lane & 15, g = lane >> 4;

  const size_t qrow0 = (size_t)bh * 2048 + qt * 128 + wv * 32;
  bf16x8 qf[2][2];
#pragma unroll
  for (int mt2 = 0; mt2 < 2; ++mt2)
#pragma unroll
    for (int kc = 0; kc < 2; ++kc)
      qf[mt2][kc] = *(const bf16x8*)&Qb[(qrow0 + mt2 * 16 + r) * 64 + kc * 32 + g * 8];

  // K/V staging: XOR source pre-swizzle, linear LDS dest (rule 21)
  const int krow = tid >> 3;                       // 0..31
  const int kcg = ((tid & 7) ^ (krow & 7)) * 8;    // swizzled source column
  const bf16_t* gK = Kb + (size_t)bh * 2048 * 64;
  const bf16_t* gV = Vt + (size_t)bh * 64 * 2048;
  bf16_t* myP = &Ps[wv][0];

  auto stageKV = [&](int t, int buf) {
    const int kv0 = t * 64;
    gload16(gK + (size_t)(kv0 + krow) * 64 + kcg, &Ks[buf][wv * 512]);
    gload16(gK + (size_t)(kv0 + 32 + krow) * 64 + kcg, &Ks[buf][2048 + wv * 512]);
    gload16(gV + (size_t)krow * 2048 + kv0 + kcg, &Vs[buf][wv * 512]);
    gload16(gV + (size_t)(32 + krow) * 2048 + kv0 + kcg, &Vs[buf][2048 + wv * 512]);
  };

  f32x4 oacc[2][4] = {};
  float lsum[2] = {0.f, 0.f};

  stageKV(0, 0);
  __syncthreads();
  int buf = 0;
  for (int t = 0; t < 32; ++t) {
    if (t < 31) stageKV(t + 1, buf ^ 1);
    // ---- S^T = K Q^T : lane holds S[q=mt2*16+r][k=ntk*16+g*4+j]
    f32x4 sacc[2][4] = {};
#pragma unroll
    for (int kc = 0; kc < 2; ++kc) {
      bf16x8 kf[4];
#pragma unroll
      for (int ntk = 0; ntk < 4; ++ntk) {
        const int row = ntk * 16 + r;
        const int cg = (kc * 4 + g) ^ (row & 7);
        kf[ntk] = *(const bf16x8*)&Ks[buf][row * 64 + cg * 8];
      }
      __builtin_amdgcn_s_setprio(1);
#pragma unroll
      for (int ntk = 0; ntk < 4; ++ntk)
#pragma unroll
        for (int mt2 = 0; mt2 < 2; ++mt2)
          sacc[mt2][ntk] = MFMA16(kf[ntk], qf[mt2][kc], sacc[mt2][ntk]);
      __builtin_amdgcn_s_setprio(0);
    }
    // ---- hoist V fragment reads (independent of P) so they overlap the
    //      exp/pack + P LDS round-trip below
    bf16x8 vf[2][4];
#pragma unroll
    for (int kc = 0; kc < 2; ++kc)
#pragma unroll
      for (int nth = 0; nth < 4; ++nth) {
        const int hrow = nth * 16 + r;
        const int cg = (kc * 4 + g) ^ (hrow & 7);
        vf[kc][nth] = *(const bf16x8*)&Vs[buf][hrow * 64 + cg * 8];
      }
    // ---- P = exp(S'), packed b64 stores into XOR-swizzled Ps
#pragma unroll
    for (int mt2 = 0; mt2 < 2; ++mt2)
#pragma unroll
      for (int ntk = 0; ntk < 4; ++ntk) {
        const f32x4 s4 = sacc[mt2][ntk];
        const float p0 = fexp2(s4[0]), p1 = fexp2(s4[1]);
        const float p2 = fexp2(s4[2]), p3 = fexp2(s4[3]);
        lsum[mt2] += (p0 + p1) + (p2 + p3);
        alignas(8) bf16_t pb[4] = {(bf16_t)p0, (bf16_t)p1, (bf16_t)p2, (bf16_t)p3};
        const int q = mt2 * 16 + r;
        const int gw = (2 * ntk + (g >> 1)) ^ (r & 7);
        *(uint2*)&myP[q * 64 + gw * 8 + (g & 1) * 4] = *(const uint2*)pb;
      }
    // ---- O += P V
#pragma unroll
    for (int kc = 0; kc < 2; ++kc) {
      bf16x8 pf[2];
#pragma unroll
      for (int mt2 = 0; mt2 < 2; ++mt2) {
        const int q = mt2 * 16 + r;
        const int gr = (kc * 4 + g) ^ (r & 7);
        pf[mt2] = *(const bf16x8*)&myP[q * 64 + gr * 8];
      }
      __builtin_amdgcn_s_setprio(1);
#pragma unroll
      for (int nth = 0; nth < 4; ++nth)
#pragma unroll
        for (int mt2 = 0; mt2 < 2; ++mt2)
          oacc[mt2][nth] = MFMA16(pf[mt2], vf[kc][nth], oacc[mt2][nth]);
      __builtin_amdgcn_s_setprio(0);
    }
    __syncthreads();
    buf ^= 1;
  }

  // full row-sums: combine the 4 g-groups (lanes r, r+16, r+32, r+48)
#pragma unroll
  for (int mt2 = 0; mt2 < 2; ++mt2) {
    lsum[mt2] += __shfl_xor(lsum[mt2], 16, 64);
    lsum[mt2] += __shfl_xor(lsum[mt2], 32, 64);
  }

  const int b = bh >> 4, h = bh & 15;
#pragma unroll
  for (int mt2 = 0; mt2 < 2; ++mt2)
#pragma unroll
    for (int j = 0; j < 4; ++j) {
      const float sum = __shfl(lsum[mt2], g * 4 + j, 64);
      const float inv = __builtin_amdgcn_rcpf(sum);
      const int s = qt * 128 + wv * 32 + mt2 * 16 + g * 4 + j;
#pragma unroll
      for (int nth = 0; nth < 4; ++nth) {
        const int col = h * 64 + nth * 16 + r;
        AO[((size_t)(b * 2048 + s)) * 1024 + col] = (bf16_t)(oacc[mt2][nth][j] * inv);
      }
    }
}

// -------------------------------------------------------------- launch ----
extern "C" void kernel_launch(void* const* d_in, const int* in_sizes, int n_in,
                              void* d_out, int out_size, void* d_ws, size_t ws_size,
                              hipStream_t stream) {
  const float* x = (const float*)d_in[0];
  const float* lA = (const float*)d_in[1];
  const float* lB = (const float*)d_in[2];
  const float* Wq = (const float*)d_in[3];
  const float* bq = (const float*)d_in[4];
  const float* Wp = (const float*)d_in[5];
  const float* bp = (const float*)d_in[6];

  char* ws = (char*)d_ws;
  bf16_t* xh  = (bf16_t*)(ws);                      // 16 MiB
  bf16_t* We  = (bf16_t*)(ws + 16777216);           // 6 MiB
  bf16_t* Wph = (bf16_t*)(ws + 23068672);           // 2 MiB
  bf16_t* Qb  = (bf16_t*)(ws + 25165824);           // 16 MiB [b,h,s,hd] (pre-scaled)
  bf16_t* Kb  = (bf16_t*)(ws + 41943040);           // 16 MiB [b,h,s,hd]
  bf16_t* Vt  = (bf16_t*)(ws + 58720256);           // 16 MiB [b,h,hd,s]
  bf16_t* AO  = (bf16_t*)(ws + 75497472);           // 16 MiB [tok,1024]

  prep_kernel<<<7680, 256, 0, stream>>>(x, lA, lB, Wq, Wp, xh, We, Wph);
  gemm128<0><<<dim3(64, 24), 256, 0, stream>>>(xh, We, bq, Qb, Kb, Vt, nullptr);
  attn_kernel<<<dim3(64, 16), 256, 0, stream>>>(Qb, Kb, Vt, AO);
  gemm128<1><<<dim3(64, 8), 256, 0, stream>>>(AO, Wph, bp, nullptr, nullptr, nullptr,
                                              (float*)d_out);
}

// Round 7
// 279.037 us; speedup vs baseline: 1.5318x; 1.0306x over previous
//
#include <hip/hip_runtime.h>
#include <hip/hip_bf16.h>

typedef __bf16 bf16_t;
typedef __bf16 bf16x8 __attribute__((ext_vector_type(8)));
typedef float f32x4 __attribute__((ext_vector_type(4)));

#define MFMA16(a, b, c) __builtin_amdgcn_mfma_f32_16x16x32_bf16((a), (b), (c), 0, 0, 0)

__device__ __forceinline__ void gload16(const bf16_t* g, bf16_t* l) {
  __builtin_amdgcn_global_load_lds((const __attribute__((address_space(1))) void*)g,
                                   (__attribute__((address_space(3))) void*)l,
                                   16, 0, 0);
}

__device__ __forceinline__ float fexp2(float x) {
  float r;
  asm("v_exp_f32 %0, %1" : "=v"(r) : "v"(x));
  return r;
}

// ---------------------------------------------------------------- prep ----
__global__ void __launch_bounds__(256)
prep_kernel(const float* __restrict__ x, const float* __restrict__ lA,
            const float* __restrict__ lB, const float* __restrict__ Wq,
            const float* __restrict__ Wp,
            bf16_t* __restrict__ xh, bf16_t* __restrict__ We,
            bf16_t* __restrict__ Wph) {
  const int bid = blockIdx.x, tid = threadIdx.x;
  if (bid < 4096) {
    const size_t i = ((size_t)bid * 256 + tid) * 8;
    const float4 f0 = ((const float4*)(x + i))[0];
    const float4 f1 = ((const float4*)(x + i))[1];
    alignas(16) bf16_t o[8] = {(bf16_t)f0.x, (bf16_t)f0.y, (bf16_t)f0.z, (bf16_t)f0.w,
                               (bf16_t)f1.x, (bf16_t)f1.y, (bf16_t)f1.z, (bf16_t)f1.w};
    *(uint4*)(xh + i) = *(const uint4*)o;
  } else if (bid < 7168) {
    const int g = (bid - 4096) * 256 + tid;
    const int e = g >> 8;
    const int d4 = (g & 255) * 4;
    float4 a = ((const float4*)(Wq + (size_t)e * 1024 + d4))[0];
#pragma unroll
    for (int r8 = 0; r8 < 8; ++r8) {
      const float sc = 0.125f * lB[e * 8 + r8];
      const float4 av = ((const float4*)(lA + r8 * 1024 + d4))[0];
      a.x += sc * av.x; a.y += sc * av.y; a.z += sc * av.z; a.w += sc * av.w;
    }
    alignas(8) bf16_t o[4] = {(bf16_t)a.x, (bf16_t)a.y, (bf16_t)a.z, (bf16_t)a.w};
    *(uint2*)(We + (size_t)e * 1024 + d4) = *(const uint2*)o;
  } else {
    const size_t i = ((size_t)(bid - 7168) * 256 + tid) * 8;
    const float4 f0 = ((const float4*)(Wp + i))[0];
    const float4 f1 = ((const float4*)(Wp + i))[1];
    alignas(16) bf16_t o[8] = {(bf16_t)f0.x, (bf16_t)f0.y, (bf16_t)f0.z, (bf16_t)f0.w,
                               (bf16_t)f1.x, (bf16_t)f1.y, (bf16_t)f1.z, (bf16_t)f1.w};
    *(uint4*)(Wph + i) = *(const uint4*)o;
  }
}

// ---------------------------------------------------------------- GEMM ----
template <int EPI>
__global__ void __launch_bounds__(256)
gemm128(const bf16_t* __restrict__ A, const bf16_t* __restrict__ Bw,
        const float* __restrict__ bias, bf16_t* __restrict__ Qb,
        bf16_t* __restrict__ Kb, bf16_t* __restrict__ Vt,
        float* __restrict__ Obuf) {
  __shared__ bf16_t Asm[2][128 * 32];
  __shared__ bf16_t Bsm[2][128 * 32];
  const int tid = threadIdx.x;
  const int lane = tid & 63;
  const int wv = tid >> 6;
  const int wm = (wv >> 1) * 64;
  const int wn = (wv & 1) * 64;
  const int tm = blockIdx.x * 128;
  const int tn = blockIdx.y * 128;
  const int K = 1024;
  const int r = lane & 15, g = lane >> 4;

  const int srow = tid >> 2;
  const int scol = (tid & 3) * 8;
  const bf16_t* gA = A + (size_t)(tm + srow) * K + scol;
  const bf16_t* gB = Bw + (size_t)(tn + srow) * K + scol;

  f32x4 acc[4][4] = {};

  auto stage = [&](int kt, int buf) {
    const int k0 = kt * 32;
    bf16_t* la = &Asm[buf][wv * 512];
    bf16_t* lb = &Bsm[buf][wv * 512];
    gload16(gA + k0, la);
    gload16(gA + (size_t)64 * K + k0, la + 2048);
    gload16(gB + k0, lb);
    gload16(gB + (size_t)64 * K + k0, lb + 2048);
  };

  auto compute = [&](int buf) {
    bf16x8 af[4], bff[4];
#pragma unroll
    for (int mt = 0; mt < 4; ++mt)
      af[mt] = *(const bf16x8*)&Asm[buf][(wm + mt * 16 + r) * 32 + g * 8];
#pragma unroll
    for (int nt = 0; nt < 4; ++nt)
      bff[nt] = *(const bf16x8*)&Bsm[buf][(wn + nt * 16 + r) * 32 + g * 8];
#pragma unroll
    for (int mt = 0; mt < 4; ++mt)
#pragma unroll
      for (int nt = 0; nt < 4; ++nt)
        acc[mt][nt] = MFMA16(af[mt], bff[nt], acc[mt][nt]);
  };

  stage(0, 0);
  __syncthreads();
  int buf = 0;
  for (int kt = 0; kt < 31; ++kt) {
    stage(kt + 1, buf ^ 1);
    compute(buf);
    __syncthreads();
    buf ^= 1;
  }
  compute(buf);

  if (EPI == 0) {
    const int which = tn >> 10;
    const float qs = (which == 0) ? 0.18033688011f : 1.0f;  // log2(e)/8 folded into Q
#pragma unroll
    for (int nt = 0; nt < 4; ++nt) {
      const int e = tn + wn + nt * 16 + r;
      const float bv = bias[e];
      const int h = (e >> 6) & 15;
      const int hd = e & 63;
#pragma unroll
      for (int mt = 0; mt < 4; ++mt) {
        const int m0 = tm + wm + mt * 16 + g * 4;
        const int b = m0 >> 11;
        const int s0 = m0 & 2047;
        const size_t bh = (size_t)(b * 16 + h);
        if (which == 2) {
          alignas(8) bf16_t tmp[4];
#pragma unroll
          for (int j = 0; j < 4; ++j) tmp[j] = (bf16_t)(acc[mt][nt][j] + bv);
          *(uint2*)&Vt[(bh * 64 + hd) * 2048 + s0] = *(const uint2*)tmp;
        } else {
          bf16_t* dst = (which == 0) ? Qb : Kb;
#pragma unroll
          for (int j = 0; j < 4; ++j)
            dst[(bh * 2048 + s0 + j) * 64 + hd] = (bf16_t)((acc[mt][nt][j] + bv) * qs);
        }
      }
    }
  } else {
#pragma unroll
    for (int nt = 0; nt < 4; ++nt) {
      const int e = tn + wn + nt * 16 + r;
      const float bv = bias[e];
#pragma unroll
      for (int mt = 0; mt < 4; ++mt) {
#pragma unroll
        for (int j = 0; j < 4; ++j) {
          const int m = tm + wm + mt * 16 + g * 4 + j;
          Obuf[(size_t)m * 1024 + e] = acc[mt][nt][j] + bv;
        }
      }
    }
  }
}

// ----------------------------------------------------------- attention ----
// R6 structure with QBLK=64 per wave (4 waves x 64 q-rows = 256 q/block,
// grid (64,8) = 512 blocks = exactly 2 blocks/CU, no tail). K/V staging
// traffic halves; per-tile barrier cost amortized over 2x MFMA. All verified
// layouts (swapped 16x16 QK^T, XOR P-swizzle, V-hoist) unchanged; mt2 loop
// [0,2) becomes m4 loop [0,4).
__global__ void __launch_bounds__(256, 2)
attn_kernel(const bf16_t* __restrict__ Qb, const bf16_t* __restrict__ Kb,
            const bf16_t* __restrict__ Vt, bf16_t* __restrict__ AO) {
  __shared__ bf16_t Ks[2][64 * 64];
  __shared__ bf16_t Vs[2][64 * 64];
  __shared__ bf16_t Ps[4][64 * 64];

  const int tid = threadIdx.x, lane = tid & 63, wv = tid >> 6;
  const int bh = blockIdx.x;
  const int qt = blockIdx.y;
  const int r = lane & 15, g = lane >> 4;

  const size_t qrow0 = (size_t)bh * 2048 + qt * 256 + wv * 64;
  bf16x8 qf[4][2];
#pragma unroll
  for (int m4 = 0; m4 < 4; ++m4)
#pragma unroll
    for (int kc = 0; kc < 2; ++kc)
      qf[m4][kc] = *(const bf16x8*)&Qb[(qrow0 + m4 * 16 + r) * 64 + kc * 32 + g * 8];

  // K/V staging: XOR source pre-swizzle, linear LDS dest (rule 21)
  const int krow = tid >> 3;                       // 0..31
  const int kcg = ((tid & 7) ^ (krow & 7)) * 8;    // swizzled source column
  const bf16_t* gK = Kb + (size_t)bh * 2048 * 64;
  const bf16_t* gV = Vt + (size_t)bh * 64 * 2048;
  bf16_t* myP = &Ps[wv][0];

  auto stageKV = [&](int t, int buf) {
    const int kv0 = t * 64;
    gload16(gK + (size_t)(kv0 + krow) * 64 + kcg, &Ks[buf][wv * 512]);
    gload16(gK + (size_t)(kv0 + 32 + krow) * 64 + kcg, &Ks[buf][2048 + wv * 512]);
    gload16(gV + (size_t)krow * 2048 + kv0 + kcg, &Vs[buf][wv * 512]);
    gload16(gV + (size_t)(32 + krow) * 2048 + kv0 + kcg, &Vs[buf][2048 + wv * 512]);
  };

  f32x4 oacc[4][4] = {};
  float lsum[4] = {0.f, 0.f, 0.f, 0.f};

  stageKV(0, 0);
  __syncthreads();
  int buf = 0;
  for (int t = 0; t < 32; ++t) {
    if (t < 31) stageKV(t + 1, buf ^ 1);
    // ---- S^T = K Q^T : lane holds S[q=m4*16+r][k=ntk*16+g*4+j]
    f32x4 sacc[4][4] = {};
#pragma unroll
    for (int kc = 0; kc < 2; ++kc) {
      bf16x8 kf[4];
#pragma unroll
      for (int ntk = 0; ntk < 4; ++ntk) {
        const int row = ntk * 16 + r;
        const int cg = (kc * 4 + g) ^ (row & 7);
        kf[ntk] = *(const bf16x8*)&Ks[buf][row * 64 + cg * 8];
      }
      __builtin_amdgcn_s_setprio(1);
#pragma unroll
      for (int ntk = 0; ntk < 4; ++ntk)
#pragma unroll
        for (int m4 = 0; m4 < 4; ++m4)
          sacc[m4][ntk] = MFMA16(kf[ntk], qf[m4][kc], sacc[m4][ntk]);
      __builtin_amdgcn_s_setprio(0);
    }
    // ---- hoist V fragment reads (independent of P) so they overlap the
    //      exp/pack + P LDS round-trip below
    bf16x8 vf[2][4];
#pragma unroll
    for (int kc = 0; kc < 2; ++kc)
#pragma unroll
      for (int nth = 0; nth < 4; ++nth) {
        const int hrow = nth * 16 + r;
        const int cg = (kc * 4 + g) ^ (hrow & 7);
        vf[kc][nth] = *(const bf16x8*)&Vs[buf][hrow * 64 + cg * 8];
      }
    // ---- P = exp(S'), packed b64 stores into XOR-swizzled Ps
#pragma unroll
    for (int m4 = 0; m4 < 4; ++m4)
#pragma unroll
      for (int ntk = 0; ntk < 4; ++ntk) {
        const f32x4 s4 = sacc[m4][ntk];
        const float p0 = fexp2(s4[0]), p1 = fexp2(s4[1]);
        const float p2 = fexp2(s4[2]), p3 = fexp2(s4[3]);
        lsum[m4] += (p0 + p1) + (p2 + p3);
        alignas(8) bf16_t pb[4] = {(bf16_t)p0, (bf16_t)p1, (bf16_t)p2, (bf16_t)p3};
        const int q = m4 * 16 + r;
        const int gw = (2 * ntk + (g >> 1)) ^ (r & 7);
        *(uint2*)&myP[q * 64 + gw * 8 + (g & 1) * 4] = *(const uint2*)pb;
      }
    // ---- O += P V
#pragma unroll
    for (int kc = 0; kc < 2; ++kc) {
      bf16x8 pf[4];
#pragma unroll
      for (int m4 = 0; m4 < 4; ++m4) {
        const int q = m4 * 16 + r;
        const int gr = (kc * 4 + g) ^ (r & 7);
        pf[m4] = *(const bf16x8*)&myP[q * 64 + gr * 8];
      }
      __builtin_amdgcn_s_setprio(1);
#pragma unroll
      for (int nth = 0; nth < 4; ++nth)
#pragma unroll
        for (int m4 = 0; m4 < 4; ++m4)
          oacc[m4][nth] = MFMA16(pf[m4], vf[kc][nth], oacc[m4][nth]);
      __builtin_amdgcn_s_setprio(0);
    }
    __syncthreads();
    buf ^= 1;
  }

  // full row-sums: combine the 4 g-groups (lanes r, r+16, r+32, r+48)
#pragma unroll
  for (int m4 = 0; m4 < 4; ++m4) {
    lsum[m4] += __shfl_xor(lsum[m4], 16, 64);
    lsum[m4] += __shfl_xor(lsum[m4], 32, 64);
  }

  const int b = bh >> 4, h = bh & 15;
#pragma unroll
  for (int m4 = 0; m4 < 4; ++m4)
#pragma unroll
    for (int j = 0; j < 4; ++j) {
      const float sum = __shfl(lsum[m4], g * 4 + j, 64);
      const float inv = __builtin_amdgcn_rcpf(sum);
      const int s = qt * 256 + wv * 64 + m4 * 16 + g * 4 + j;
#pragma unroll
      for (int nth = 0; nth < 4; ++nth) {
        const int col = h * 64 + nth * 16 + r;
        AO[((size_t)(b * 2048 + s)) * 1024 + col] = (bf16_t)(oacc[m4][nth][j] * inv);
      }
    }
}

// -------------------------------------------------------------- launch ----
extern "C" void kernel_launch(void* const* d_in, const int* in_sizes, int n_in,
                              void* d_out, int out_size, void* d_ws, size_t ws_size,
                              hipStream_t stream) {
  const float* x = (const float*)d_in[0];
  const float* lA = (const float*)d_in[1];
  const float* lB = (const float*)d_in[2];
  const float* Wq = (const float*)d_in[3];
  const float* bq = (const float*)d_in[4];
  const float* Wp = (const float*)d_in[5];
  const float* bp = (const float*)d_in[6];

  char* ws = (char*)d_ws;
  bf16_t* xh  = (bf16_t*)(ws);                      // 16 MiB
  bf16_t* We  = (bf16_t*)(ws + 16777216);           // 6 MiB
  bf16_t* Wph = (bf16_t*)(ws + 23068672);           // 2 MiB
  bf16_t* Qb  = (bf16_t*)(ws + 25165824);           // 16 MiB [b,h,s,hd] (pre-scaled)
  bf16_t* Kb  = (bf16_t*)(ws + 41943040);           // 16 MiB [b,h,s,hd]
  bf16_t* Vt  = (bf16_t*)(ws + 58720256);           // 16 MiB [b,h,hd,s]
  bf16_t* AO  = (bf16_t*)(ws + 75497472);           // 16 MiB [tok,1024]

  prep_kernel<<<7680, 256, 0, stream>>>(x, lA, lB, Wq, Wp, xh, We, Wph);
  gemm128<0><<<dim3(64, 24), 256, 0, stream>>>(xh, We, bq, Qb, Kb, Vt, nullptr);
  attn_kernel<<<dim3(64, 8), 256, 0, stream>>>(Qb, Kb, Vt, AO);
  gemm128<1><<<dim3(64, 8), 256, 0, stream>>>(AO, Wph, bp, nullptr, nullptr, nullptr,
                                              (float*)d_out);
}